// Round 2
// baseline (1158.992 us; speedup 1.0000x reference)
//
#include <hip/hip_runtime.h>
#include <hip/hip_bf16.h>

typedef unsigned short u16;
typedef unsigned int u32;
typedef __bf16 bf16x8 __attribute__((ext_vector_type(8)));
typedef float f32x4 __attribute__((ext_vector_type(4)));

#define DEV static __device__ __forceinline__

DEV u16 f2bf(float f) {
  __bf16 b = (__bf16)f;  // fptrunc float->bfloat is RNE
  return __builtin_bit_cast(u16, b);
}
DEV float bf2f(u16 x) { return __builtin_bit_cast(float, (u32)x << 16); }

DEV void gload_lds16(const void* g, void* l) {
  __builtin_amdgcn_global_load_lds(
      (const __attribute__((address_space(1))) void*)g,
      (__attribute__((address_space(3))) void*)l, 16, 0, 0);
}

// ---------------- weight f32 -> bf16 conversion ----------------
__global__ __launch_bounds__(256) void cvt_bf16(const float* __restrict__ src,
                                                u16* __restrict__ dst, int n4) {
  int t = blockIdx.x * 256 + threadIdx.x;
  if (t >= n4) return;
  float4 v = *(const float4*)(src + (size_t)t * 4);
  ushort4 o;
  o.x = f2bf(v.x); o.y = f2bf(v.y); o.z = f2bf(v.z); o.w = f2bf(v.w);
  *(ushort4*)(dst + (size_t)t * 4) = o;
}

// ---------------- initial gather: X0 = bf16(emb_item[items[:,0]]) ----------------
__global__ __launch_bounds__(256) void gather0(const int* __restrict__ items,
                                               const float* __restrict__ emb,
                                               u16* __restrict__ out) {
  int t = blockIdx.x * 256 + threadIdx.x;  // B*256 threads, 4 elems each
  int b = t >> 8;
  int d = (t & 255) << 2;
  int it = items[b * 3];
  float4 v = *(const float4*)(emb + (size_t)it * 1024 + d);
  ushort4 o;
  o.x = f2bf(v.x); o.y = f2bf(v.y); o.z = f2bf(v.z); o.w = f2bf(v.w);
  *(ushort4*)(out + (size_t)b * 1024 + d) = o;
}

// ---------------- main bf16 MFMA GEMM, 128x128 tile, BK=64 ----------------
// out[m][nc] = sum_k A[m][k] * W[nc][k]   (pointers for bias/emb/out/resid are
// pre-offset to the column-chunk base; lda/ldw/ldr/ldo are full row strides)
__global__ __launch_bounds__(256) void gemm_bf16(
    const u16* __restrict__ A, int lda,
    const u16* __restrict__ W, int ldw,
    int K, int nbn,
    const float* __restrict__ bias,
    const float* __restrict__ emb, int emb_ld,
    const int* __restrict__ idx, int idx_stride, int idx_off,
    const u16* __restrict__ resid, int ldr,
    int do_relu,
    u16* __restrict__ out, int ldo) {
  __shared__ __align__(16) u16 ldsA[128 * 64];
  __shared__ __align__(16) u16 ldsB[128 * 64];

  const int t = threadIdx.x;
  const int lane = t & 63;
  const int wave = t >> 6;

  // XCD-bijective swizzle (all launches use nwg % 8 == 0)
  const int nwg = gridDim.x;
  const int bid = blockIdx.x;
  const int cpx = nwg >> 3;
  const int wg = (bid & 7) * cpx + (bid >> 3);
  const int bm = wg / nbn, bn = wg % nbn;
  const int tile_m = bm * 128, tile_n = bn * 128;

  const int wr = (wave >> 1) * 64;  // wave row offset in tile
  const int wc = (wave & 1) * 64;   // wave col offset in tile

  f32x4 acc[4][4] = {};

  const int nkt = K >> 6;
  for (int kt = 0; kt < nkt; ++kt) {
    const int k0 = kt << 6;
    // stage A tile (128x64 bf16 = 16KB), XOR-swizzled via pre-swizzled source
#pragma unroll
    for (int j = 0; j < 4; ++j) {
      int L = j * 256 + t;           // linear 16B-chunk index in LDS
      int row = L >> 3;              // tile row
      int g8 = (L & 7) ^ (row & 7);  // source k-chunk (pre-swizzled)
      gload_lds16(A + ((size_t)(tile_m + row) * lda + k0 + g8 * 8), &ldsA[L * 8]);
    }
#pragma unroll
    for (int j = 0; j < 4; ++j) {
      int L = j * 256 + t;
      int row = L >> 3;
      int g8 = (L & 7) ^ (row & 7);
      gload_lds16(W + ((size_t)(tile_n + row) * ldw + k0 + g8 * 8), &ldsB[L * 8]);
    }
    __syncthreads();
    // compute: 2 K-steps of 32
#pragma unroll
    for (int kk = 0; kk < 2; ++kk) {
      bf16x8 af[4], bfr[4];
      const int k8 = kk * 4 + (lane >> 4);
#pragma unroll
      for (int mi = 0; mi < 4; ++mi) {
        int r = wr + mi * 16 + (lane & 15);
        af[mi] = *(const bf16x8*)&ldsA[r * 64 + ((k8 ^ (r & 7)) * 8)];
      }
#pragma unroll
      for (int ni = 0; ni < 4; ++ni) {
        int c = wc + ni * 16 + (lane & 15);
        bfr[ni] = *(const bf16x8*)&ldsB[c * 64 + ((k8 ^ (c & 7)) * 8)];
      }
#pragma unroll
      for (int mi = 0; mi < 4; ++mi)
#pragma unroll
        for (int ni = 0; ni < 4; ++ni)
          acc[mi][ni] = __builtin_amdgcn_mfma_f32_16x16x32_bf16(
              af[mi], bfr[ni], acc[mi][ni], 0, 0, 0);
    }
    __syncthreads();
  }

  // epilogue: C/D layout col=lane&15, row=(lane>>4)*4+reg
#pragma unroll
  for (int mi = 0; mi < 4; ++mi) {
#pragma unroll
    for (int r = 0; r < 4; ++r) {
      const int grow = tile_m + wr + mi * 16 + (lane >> 4) * 4 + r;
      int eidx = 0;
      if (emb) eidx = idx[grow * idx_stride + idx_off];
#pragma unroll
      for (int ni = 0; ni < 4; ++ni) {
        const int gcol = tile_n + wc + ni * 16 + (lane & 15);
        float v = acc[mi][ni][r];
        if (bias) v += bias[gcol];
        if (emb) v += emb[(size_t)eidx * emb_ld + gcol];
        if (resid) v += bf2f(resid[(size_t)grow * ldr + gcol]);
        if (do_relu) v = fmaxf(v, 0.f);
        out[(size_t)grow * ldo + gcol] = f2bf(v);
      }
    }
  }
}

// ---------------- final out = Y(bf16) @ W3.T  (f32 accum, N=7) ----------------
__global__ __launch_bounds__(256) void final_w3(const u16* __restrict__ Y,
                                                const float* __restrict__ W3,
                                                float* __restrict__ out) {
  const int lane = threadIdx.x & 63, wave = threadIdx.x >> 6;
#pragma unroll
  for (int r = 0; r < 4; ++r) {
    const int row = blockIdx.x * 16 + wave * 4 + r;
    float acc[7] = {0, 0, 0, 0, 0, 0, 0};
#pragma unroll
    for (int it = 0; it < 4; ++it) {
      const int k = it * 256 + lane * 4;
      ushort4 yv = *(const ushort4*)(Y + (size_t)row * 1024 + k);
      float y0 = bf2f(yv.x), y1 = bf2f(yv.y), y2 = bf2f(yv.z), y3 = bf2f(yv.w);
#pragma unroll
      for (int n = 0; n < 7; ++n) {
        float4 w = *(const float4*)(W3 + (size_t)n * 1024 + k);
        acc[n] += y0 * w.x + y1 * w.y + y2 * w.z + y3 * w.w;
      }
    }
#pragma unroll
    for (int n = 0; n < 7; ++n)
#pragma unroll
      for (int off = 32; off > 0; off >>= 1)
        acc[n] += __shfl_down(acc[n], off);
    if (lane == 0) {
#pragma unroll
      for (int n = 0; n < 7; ++n) out[(size_t)row * 7 + n] = acc[n];
    }
  }
}

extern "C" void kernel_launch(void* const* d_in, const int* in_sizes, int n_in,
                              void* d_out, int out_size, void* d_ws, size_t ws_size,
                              hipStream_t stream) {
  const int* items = (const int*)d_in[0];
  const int* attr = (const int*)d_in[1];
  const int* perm = (const int*)d_in[2];
  const float* emb_item = (const float*)d_in[3];
  const float* W2 = (const float*)d_in[4];
  const float* W3 = (const float*)d_in[5];
  const float* emb_attr = (const float*)d_in[6];
  const float* W4 = (const float*)d_in[7];
  const float* b4 = (const float*)d_in[8];
  const float* W5 = (const float*)d_in[9];
  const float* W8u = (const float*)d_in[10];
  const float* b8u = (const float*)d_in[11];
  const float* W8d = (const float*)d_in[12];
  const float* b8d = (const float*)d_in[13];
  const float* emb_perm = (const float*)d_in[14];

  const int B = 16384, DIM = 1024, HID = 4096;

  char* ws = (char*)d_ws;
  size_t off = 0;
  auto alloc = [&](size_t bytes) {
    void* p = ws + off;
    off += (bytes + 255) & ~255ull;
    return p;
  };
  u16* W2b = (u16*)alloc((size_t)DIM * DIM * 2);
  u16* W4b = (u16*)alloc((size_t)HID * DIM * 2);
  u16* W5b = (u16*)alloc((size_t)DIM * HID * 2);
  u16* W8ub = (u16*)alloc((size_t)HID * DIM * 2);
  u16* W8db = (u16*)alloc((size_t)DIM * HID * 2);
  u16* X0 = (u16*)alloc((size_t)B * DIM * 2);
  u16* X1 = (u16*)alloc((size_t)B * DIM * 2);

  // Adaptive hidden-chunk size so we never overflow d_ws.
  size_t fixed = off;
  int HC = 4096;
  while (HC > 256 && fixed + (size_t)B * HC * 2 > ws_size) HC >>= 1;
  u16* Hc = (u16*)alloc((size_t)B * HC * 2);
  const int nch = HID / HC;

  // weights -> bf16
  cvt_bf16<<<(DIM * DIM / 4 + 255) / 256, 256, 0, stream>>>(W2, W2b, DIM * DIM / 4);
  cvt_bf16<<<(HID * DIM / 4 + 255) / 256, 256, 0, stream>>>(W4, W4b, HID * DIM / 4);
  cvt_bf16<<<(HID * DIM / 4 + 255) / 256, 256, 0, stream>>>(W5, W5b, HID * DIM / 4);
  cvt_bf16<<<(HID * DIM / 4 + 255) / 256, 256, 0, stream>>>(W8u, W8ub, HID * DIM / 4);
  cvt_bf16<<<(HID * DIM / 4 + 255) / 256, 256, 0, stream>>>(W8d, W8db, HID * DIM / 4);

  // X0 = bf16(emb_item[items[:,0]])
  gather0<<<B, 256, 0, stream>>>(items, emb_item, X0);

  // ---- encoder: 3x (state @ W2^T + next_emb) ----
  gemm_bf16<<<1024, 256, 0, stream>>>(X0, DIM, W2b, DIM, DIM, 8,
      nullptr, emb_item, DIM, items, 3, 1, nullptr, 0, 0, X1, DIM);
  gemm_bf16<<<1024, 256, 0, stream>>>(X1, DIM, W2b, DIM, DIM, 8,
      nullptr, emb_item, DIM, items, 3, 2, nullptr, 0, 0, X0, DIM);
  // y = state3 + emb_attr[attr]  -> X1
  gemm_bf16<<<1024, 256, 0, stream>>>(X0, DIM, W2b, DIM, DIM, 8,
      nullptr, emb_attr, DIM, attr, 1, 0, nullptr, 0, 0, X1, DIM);

  // ---- FFN1: y1 = y + relu(y@W4^T + b4)@W5^T  (X1 -> X0) ----
  for (int c = 0; c < nch; ++c) {
    gemm_bf16<<<128 * (HC / 128), 256, 0, stream>>>(
        X1, DIM, W4b + (size_t)c * HC * DIM, DIM, DIM, HC / 128,
        b4 + c * HC, nullptr, 0, nullptr, 0, 0, nullptr, 0, 1, Hc, HC);
    gemm_bf16<<<1024, 256, 0, stream>>>(
        Hc, HC, W5b + (size_t)c * HC, HID, HC, 8,
        nullptr, nullptr, 0, nullptr, 0, 0,
        (c == 0 ? X1 : X0), DIM, 0, X0, DIM);
  }

  // ---- FFN2: y2 = y1 + (relu(y1@W8u^T + b8u + emb_perm[perm])@W8d^T + b8d)  (X0 -> X1) ----
  for (int c = 0; c < nch; ++c) {
    gemm_bf16<<<128 * (HC / 128), 256, 0, stream>>>(
        X0, DIM, W8ub + (size_t)c * HC * DIM, DIM, DIM, HC / 128,
        b8u + c * HC, emb_perm + c * HC, HID, perm, 1, 0, nullptr, 0, 1, Hc, HC);
    gemm_bf16<<<1024, 256, 0, stream>>>(
        Hc, HC, W8db + (size_t)c * HC, HID, HC, 8,
        (c == nch - 1 ? b8d : nullptr), nullptr, 0, nullptr, 0, 0,
        (c == 0 ? X0 : X1), DIM, 0, X1, DIM);
  }

  // out = y2 @ W3^T (f32 accum)
  final_w3<<<B / 16, 256, 0, stream>>>(X1, W3, (float*)d_out);
}

// Round 3
// 927.277 us; speedup vs baseline: 1.2499x; 1.2499x over previous
//
#include <hip/hip_runtime.h>
#include <hip/hip_bf16.h>

typedef unsigned short u16;
typedef unsigned int u32;
typedef __bf16 bf16x8 __attribute__((ext_vector_type(8)));
typedef float f32x4 __attribute__((ext_vector_type(4)));

#define DEV static __device__ __forceinline__

DEV u16 f2bf(float f) {
  __bf16 b = (__bf16)f;
  return __builtin_bit_cast(u16, b);
}
DEV float bf2f(u16 x) { return __builtin_bit_cast(float, (u32)x << 16); }

DEV void gload_lds16(const void* g, void* l) {
  __builtin_amdgcn_global_load_lds(
      (const __attribute__((address_space(1))) void*)g,
      (__attribute__((address_space(3))) void*)l, 16, 0, 0);
}

// ---------------- weight f32 -> bf16 conversion ----------------
__global__ __launch_bounds__(256) void cvt_bf16(const float* __restrict__ src,
                                                u16* __restrict__ dst, int n4) {
  int t = blockIdx.x * 256 + threadIdx.x;
  if (t >= n4) return;
  float4 v = *(const float4*)(src + (size_t)t * 4);
  ushort4 o;
  o.x = f2bf(v.x); o.y = f2bf(v.y); o.z = f2bf(v.z); o.w = f2bf(v.w);
  *(ushort4*)(dst + (size_t)t * 4) = o;
}

// ---------------- initial gather: X0 = bf16(emb_item[items[:,0]]) ----------------
__global__ __launch_bounds__(256) void gather0(const int* __restrict__ items,
                                               const float* __restrict__ emb,
                                               u16* __restrict__ out) {
  int t = blockIdx.x * 256 + threadIdx.x;
  int b = t >> 8;
  int d = (t & 255) << 2;
  int it = items[b * 3];
  float4 v = *(const float4*)(emb + (size_t)it * 1024 + d);
  ushort4 o;
  o.x = f2bf(v.x); o.y = f2bf(v.y); o.z = f2bf(v.z); o.w = f2bf(v.w);
  *(ushort4*)(out + (size_t)b * 1024 + d) = o;
}

// =====================================================================
// 256x256-tile 8-phase bf16 MFMA GEMM (T2 chunk-XOR swizzle + T3/T4
// counted vmcnt + T5 setprio). 512 threads = 8 waves (2M x 4N).
// out[m][n] = sum_k A[m][k]*W[n][k]; fused epilogue.
// =====================================================================

// stage one full 256x64 bf16 tile (2048 x 16B chunks) = 4 gloads/thread.
// LDS dest linear; global source k-chunk pre-swizzled by (row&7).
DEV void stage_tile(const u16* __restrict__ src, int ld, int row0, int k0,
                    u16* ldsbase, int t) {
#pragma unroll
  for (int q = 0; q < 4; ++q) {
    int L = q * 512 + t;
    int row = L >> 3;
    int g8 = (L & 7) ^ (row & 7);
    gload_lds16(src + ((size_t)(row0 + row) * ld + k0 + g8 * 8),
                ldsbase + (size_t)L * 8);
  }
}

DEV bf16x8 frag(const u16* base, int r, int k8) {
  return *(const bf16x8*)(base + r * 64 + ((k8 ^ (r & 7)) << 3));
}

#define PRIO_MFMA(MH, AV, BV)                                              \
  __builtin_amdgcn_s_setprio(1);                                           \
  _Pragma("unroll") for (int mi_ = 0; mi_ < 4; ++mi_) {                    \
    _Pragma("unroll") for (int nj_ = 0; nj_ < 4; ++nj_)                    \
        acc[(MH)*4 + mi_][nj_] = __builtin_amdgcn_mfma_f32_16x16x32_bf16(  \
            AV[mi_], BV[nj_], acc[(MH)*4 + mi_][nj_], 0, 0, 0);            \
  }                                                                        \
  __builtin_amdgcn_s_setprio(0);

#define BAR() __builtin_amdgcn_s_barrier()
#define LGKM0() asm volatile("s_waitcnt lgkmcnt(0)" ::: "memory")

__global__ __launch_bounds__(512, 2) void gemm256(
    const u16* __restrict__ A, int lda,
    const u16* __restrict__ W, int ldw,
    int K, int nbn,
    const float* __restrict__ bias,
    const float* __restrict__ emb, int emb_ld,
    const int* __restrict__ idx, int idx_stride, int idx_off,
    const u16* __restrict__ resid, int ldr,
    int do_relu,
    u16* __restrict__ out, int ldo) {
  // [0]=A buf0, [1]=A buf1, [2]=B buf0, [3]=B buf1  (each 256x64 bf16)
  __shared__ __align__(16) u16 lds[4][256 * 64];
  u16* AB0 = lds[0]; u16* AB1 = lds[1];
  u16* BB0 = lds[2]; u16* BB1 = lds[3];

  const int t = threadIdx.x;
  const int lane = t & 63;
  const int wave = t >> 6;
  const int lm = lane & 15;
  const int l4 = lane >> 4;

  // XCD-bijective swizzle (all launches have nwg % 8 == 0)
  const int nwg = gridDim.x;
  const int bid = blockIdx.x;
  const int cpx = nwg >> 3;
  const int wg = (bid & 7) * cpx + (bid >> 3);
  const int bm = wg / nbn, bn = wg % nbn;
  const int tile_m = bm * 256, tile_n = bn * 256;

  const int wr = (wave >> 2) * 128;  // wave row offset (0/128)
  const int wc = (wave & 3) * 64;    // wave col offset (0/64/128/192)

  f32x4 acc[8][4] = {};

  const int nkt = K >> 6;
  const int niter = nkt >> 1;

  // ---- prologue: A(t0)->AB0, B(t0)->BB0, B(t1)->BB1 (12 gloads) ----
  stage_tile(A, lda, tile_m, 0, AB0, t);
  stage_tile(W, ldw, tile_n, 0, BB0, t);
  stage_tile(W, ldw, tile_n, 64, BB1, t);
  asm volatile("s_waitcnt vmcnt(4)" ::: "memory");  // t0 landed; B(t1) in flight
  BAR();

  for (int it = 0; it < niter; ++it) {
    const bool last = (it == niter - 1);
    const int k0 = it * 128;

    // ---- P1: read t0 k0 (A m0-3 + B); stage A(t1)->AB1 ----
    bf16x8 a0[4], b0[4];
#pragma unroll
    for (int mi = 0; mi < 4; ++mi) a0[mi] = frag(AB0, wr + mi * 16 + lm, l4);
#pragma unroll
    for (int nj = 0; nj < 4; ++nj) b0[nj] = frag(BB0, wc + nj * 16 + lm, l4);
    stage_tile(A, lda, tile_m, k0 + 64, AB1, t);
    BAR(); LGKM0();
    PRIO_MFMA(0, a0, b0)
    BAR();

    // ---- P2: read t0 k0 A m4-7 ----
    bf16x8 a1[4];
#pragma unroll
    for (int mi = 0; mi < 4; ++mi) a1[mi] = frag(AB0, wr + (mi + 4) * 16 + lm, l4);
    BAR(); LGKM0();
    PRIO_MFMA(1, a1, b0)
    BAR();

    // ---- P3: read t0 k1 (A m0-7 + B) ----
    bf16x8 a2[4], a3[4], b1[4];
#pragma unroll
    for (int mi = 0; mi < 4; ++mi) a2[mi] = frag(AB0, wr + mi * 16 + lm, 4 + l4);
#pragma unroll
    for (int mi = 0; mi < 4; ++mi) a3[mi] = frag(AB0, wr + (mi + 4) * 16 + lm, 4 + l4);
#pragma unroll
    for (int nj = 0; nj < 4; ++nj) b1[nj] = frag(BB0, wc + nj * 16 + lm, 4 + l4);
    BAR(); LGKM0();
    PRIO_MFMA(0, a2, b1)
    BAR();

    // ---- P4: stage A(t2)->AB0 (buf0-A free since P3-close); gate for t1 ----
    if (!last) stage_tile(A, lda, tile_m, k0 + 128, AB0, t);
    PRIO_MFMA(1, a3, b1)
    if (last) { asm volatile("s_waitcnt vmcnt(0)" ::: "memory"); }
    else      { asm volatile("s_waitcnt vmcnt(4)" ::: "memory"); }
    BAR();

    // ---- P5: read t1 k0 (A m0-3 + B); stage B(t2)->BB0 ----
    bf16x8 c0[4], d0[4];
#pragma unroll
    for (int mi = 0; mi < 4; ++mi) c0[mi] = frag(AB1, wr + mi * 16 + lm, l4);
#pragma unroll
    for (int nj = 0; nj < 4; ++nj) d0[nj] = frag(BB1, wc + nj * 16 + lm, l4);
    if (!last) stage_tile(W, ldw, tile_n, k0 + 128, BB0, t);
    BAR(); LGKM0();
    PRIO_MFMA(0, c0, d0)
    BAR();

    // ---- P6: read t1 k0 A m4-7 ----
    bf16x8 c1[4];
#pragma unroll
    for (int mi = 0; mi < 4; ++mi) c1[mi] = frag(AB1, wr + (mi + 4) * 16 + lm, l4);
    BAR(); LGKM0();
    PRIO_MFMA(1, c1, d0)
    BAR();

    // ---- P7: read t1 k1 (A m0-7 + B) ----
    bf16x8 c2[4], c3[4], d1[4];
#pragma unroll
    for (int mi = 0; mi < 4; ++mi) c2[mi] = frag(AB1, wr + mi * 16 + lm, 4 + l4);
#pragma unroll
    for (int mi = 0; mi < 4; ++mi) c3[mi] = frag(AB1, wr + (mi + 4) * 16 + lm, 4 + l4);
#pragma unroll
    for (int nj = 0; nj < 4; ++nj) d1[nj] = frag(BB1, wc + nj * 16 + lm, 4 + l4);
    BAR(); LGKM0();
    PRIO_MFMA(0, c2, d1)
    BAR();

    // ---- P8: stage B(t3)->BB1 (buf1-B free since P7-close); gate for t2 ----
    if (!last) stage_tile(W, ldw, tile_n, k0 + 192, BB1, t);
    PRIO_MFMA(1, c3, d1)
    if (!last) {
      asm volatile("s_waitcnt vmcnt(4)" ::: "memory");
      BAR();
    }
  }

  // ---- epilogue: C/D layout col=lane&15, row=(lane>>4)*4+reg ----
#pragma unroll
  for (int mi = 0; mi < 8; ++mi) {
#pragma unroll
    for (int r = 0; r < 4; ++r) {
      const int grow = tile_m + wr + mi * 16 + l4 * 4 + r;
      int eidx = 0;
      if (emb) eidx = idx[grow * idx_stride + idx_off];
#pragma unroll
      for (int nj = 0; nj < 4; ++nj) {
        const int gcol = tile_n + wc + nj * 16 + lm;
        float v = acc[mi][nj][r];
        if (bias) v += bias[gcol];
        if (emb) v += emb[(size_t)eidx * emb_ld + gcol];
        if (resid) v += bf2f(resid[(size_t)grow * ldr + gcol]);
        if (do_relu) v = fmaxf(v, 0.f);
        out[(size_t)grow * ldo + gcol] = f2bf(v);
      }
    }
  }
}

// ---------------- final out = Y(bf16) @ W3.T  (f32 accum, N=7) ----------------
__global__ __launch_bounds__(256) void final_w3(const u16* __restrict__ Y,
                                                const float* __restrict__ W3,
                                                float* __restrict__ out) {
  const int lane = threadIdx.x & 63, wave = threadIdx.x >> 6;
#pragma unroll
  for (int r = 0; r < 4; ++r) {
    const int row = blockIdx.x * 16 + wave * 4 + r;
    float acc[7] = {0, 0, 0, 0, 0, 0, 0};
#pragma unroll
    for (int it = 0; it < 4; ++it) {
      const int k = it * 256 + lane * 4;
      ushort4 yv = *(const ushort4*)(Y + (size_t)row * 1024 + k);
      float y0 = bf2f(yv.x), y1 = bf2f(yv.y), y2 = bf2f(yv.z), y3 = bf2f(yv.w);
#pragma unroll
      for (int n = 0; n < 7; ++n) {
        float4 w = *(const float4*)(W3 + (size_t)n * 1024 + k);
        acc[n] += y0 * w.x + y1 * w.y + y2 * w.z + y3 * w.w;
      }
    }
#pragma unroll
    for (int n = 0; n < 7; ++n)
#pragma unroll
      for (int off = 32; off > 0; off >>= 1)
        acc[n] += __shfl_down(acc[n], off);
    if (lane == 0) {
#pragma unroll
      for (int n = 0; n < 7; ++n) out[(size_t)row * 7 + n] = acc[n];
    }
  }
}

extern "C" void kernel_launch(void* const* d_in, const int* in_sizes, int n_in,
                              void* d_out, int out_size, void* d_ws, size_t ws_size,
                              hipStream_t stream) {
  const int* items = (const int*)d_in[0];
  const int* attr = (const int*)d_in[1];
  const int* perm = (const int*)d_in[2];
  const float* emb_item = (const float*)d_in[3];
  const float* W2 = (const float*)d_in[4];
  const float* W3 = (const float*)d_in[5];
  const float* emb_attr = (const float*)d_in[6];
  const float* W4 = (const float*)d_in[7];
  const float* b4 = (const float*)d_in[8];
  const float* W5 = (const float*)d_in[9];
  const float* W8u = (const float*)d_in[10];
  const float* b8u = (const float*)d_in[11];
  const float* W8d = (const float*)d_in[12];
  const float* b8d = (const float*)d_in[13];
  const float* emb_perm = (const float*)d_in[14];

  const int B = 16384, DIM = 1024, HID = 4096;

  char* ws = (char*)d_ws;
  size_t off = 0;
  auto alloc = [&](size_t bytes) {
    void* p = ws + off;
    off += (bytes + 255) & ~255ull;
    return p;
  };
  u16* W2b = (u16*)alloc((size_t)DIM * DIM * 2);
  u16* W4b = (u16*)alloc((size_t)HID * DIM * 2);
  u16* W5b = (u16*)alloc((size_t)DIM * HID * 2);
  u16* W8ub = (u16*)alloc((size_t)HID * DIM * 2);
  u16* W8db = (u16*)alloc((size_t)DIM * HID * 2);
  u16* X0 = (u16*)alloc((size_t)B * DIM * 2);
  u16* X1 = (u16*)alloc((size_t)B * DIM * 2);

  // Adaptive hidden-chunk size (multiples of 256) so we never overflow d_ws.
  size_t fixed = off;
  int HC = 4096;
  while (HC > 256 && fixed + (size_t)B * HC * 2 > ws_size) HC >>= 1;
  u16* Hc = (u16*)alloc((size_t)B * HC * 2);
  const int nch = HID / HC;

  // weights -> bf16
  cvt_bf16<<<(DIM * DIM / 4 + 255) / 256, 256, 0, stream>>>(W2, W2b, DIM * DIM / 4);
  cvt_bf16<<<(HID * DIM / 4 + 255) / 256, 256, 0, stream>>>(W4, W4b, HID * DIM / 4);
  cvt_bf16<<<(HID * DIM / 4 + 255) / 256, 256, 0, stream>>>(W5, W5b, HID * DIM / 4);
  cvt_bf16<<<(HID * DIM / 4 + 255) / 256, 256, 0, stream>>>(W8u, W8ub, HID * DIM / 4);
  cvt_bf16<<<(HID * DIM / 4 + 255) / 256, 256, 0, stream>>>(W8d, W8db, HID * DIM / 4);

  // X0 = bf16(emb_item[items[:,0]])
  gather0<<<B, 256, 0, stream>>>(items, emb_item, X0);

  const int GM = B / 256;  // 64 m-tiles

  // ---- encoder: 3x (state @ W2^T + next_emb) ----
  gemm256<<<GM * (DIM / 256), 512, 0, stream>>>(X0, DIM, W2b, DIM, DIM, DIM / 256,
      nullptr, emb_item, DIM, items, 3, 1, nullptr, 0, 0, X1, DIM);
  gemm256<<<GM * (DIM / 256), 512, 0, stream>>>(X1, DIM, W2b, DIM, DIM, DIM / 256,
      nullptr, emb_item, DIM, items, 3, 2, nullptr, 0, 0, X0, DIM);
  gemm256<<<GM * (DIM / 256), 512, 0, stream>>>(X0, DIM, W2b, DIM, DIM, DIM / 256,
      nullptr, emb_attr, DIM, attr, 1, 0, nullptr, 0, 0, X1, DIM);

  // ---- FFN1: y1 = y + relu(y@W4^T + b4)@W5^T  (X1 -> X0) ----
  for (int c = 0; c < nch; ++c) {
    gemm256<<<GM * (HC / 256), 512, 0, stream>>>(
        X1, DIM, W4b + (size_t)c * HC * DIM, DIM, DIM, HC / 256,
        b4 + c * HC, nullptr, 0, nullptr, 0, 0, nullptr, 0, 1, Hc, HC);
    gemm256<<<GM * (DIM / 256), 512, 0, stream>>>(
        Hc, HC, W5b + (size_t)c * HC, HID, HC, DIM / 256,
        nullptr, nullptr, 0, nullptr, 0, 0,
        (c == 0 ? X1 : X0), DIM, 0, X0, DIM);
  }

  // ---- FFN2: y2 = y1 + (relu(y1@W8u^T + b8u + emb_perm[perm])@W8d^T + b8d) ----
  for (int c = 0; c < nch; ++c) {
    gemm256<<<GM * (HC / 256), 512, 0, stream>>>(
        X0, DIM, W8ub + (size_t)c * HC * DIM, DIM, DIM, HC / 256,
        b8u + c * HC, emb_perm + c * HC, HID, perm, 1, 0, nullptr, 0, 1, Hc, HC);
    gemm256<<<GM * (DIM / 256), 512, 0, stream>>>(
        Hc, HC, W8db + (size_t)c * HC, HID, HC, DIM / 256,
        (c == nch - 1 ? b8d : nullptr), nullptr, 0, nullptr, 0, 0,
        (c == 0 ? X0 : X1), DIM, 0, X1, DIM);
  }

  // out = y2 @ W3^T (f32 accum)
  final_w3<<<B / 16, 256, 0, stream>>>(X1, W3, (float*)d_out);
}

// Round 4
// 422.520 us; speedup vs baseline: 2.7430x; 2.1946x over previous
//
#include <hip/hip_runtime.h>
#include <hip/hip_bf16.h>

typedef unsigned short u16;
typedef unsigned int u32;
typedef __bf16 bf16x8 __attribute__((ext_vector_type(8)));
typedef float f32x4 __attribute__((ext_vector_type(4)));

#define DEV static __device__ __forceinline__

// 3087 = 7*7*7*3*3 distinct (items, attr, perm) combos; padded to 3328 rows.
#define MU 3087
#define MUPAD 3328

DEV u16 f2bf(float f) {
  __bf16 b = (__bf16)f;
  return __builtin_bit_cast(u16, b);
}
DEV float bf2f(u16 x) { return __builtin_bit_cast(float, (u32)x << 16); }

DEV void gload_lds16(const void* g, void* l) {
  __builtin_amdgcn_global_load_lds(
      (const __attribute__((address_space(1))) void*)g,
      (__attribute__((address_space(3))) void*)l, 16, 0, 0);
}

// embedding index from unique-row id: (min(u,MU-1)/div) % mod
DEV int uidx(int grow, int ediv, int emod) {
  u32 u = (u32)(grow > MU - 1 ? MU - 1 : grow);
  return (int)((u / (u32)ediv) % (u32)emod);
}

// ---------------- weight f32 -> bf16 conversion ----------------
__global__ __launch_bounds__(256) void cvt_bf16(const float* __restrict__ src,
                                                u16* __restrict__ dst, int n4) {
  int t = blockIdx.x * 256 + threadIdx.x;
  if (t >= n4) return;
  float4 v = *(const float4*)(src + (size_t)t * 4);
  ushort4 o;
  o.x = f2bf(v.x); o.y = f2bf(v.y); o.z = f2bf(v.z); o.w = f2bf(v.w);
  *(ushort4*)(dst + (size_t)t * 4) = o;
}

// ------------- initial gather over unique rows: X0[u] = emb_item[i0(u)] -------------
__global__ __launch_bounds__(256) void gather0u(const float* __restrict__ emb,
                                                u16* __restrict__ out) {
  int u = blockIdx.x;               // MUPAD rows
  int d = threadIdx.x * 4;
  int uc = u > MU - 1 ? MU - 1 : u;
  int i0 = uc / 441;                // u = ((i0*7+i1)*7+i2)*9 + a*3 + p
  float4 v = *(const float4*)(emb + (size_t)i0 * 1024 + d);
  ushort4 o;
  o.x = f2bf(v.x); o.y = f2bf(v.y); o.z = f2bf(v.z); o.w = f2bf(v.w);
  *(ushort4*)(out + (size_t)u * 1024 + d) = o;
}

// =====================================================================
// 128x128-tile 2-phase bf16 MFMA GEMM (m97 structure, chunk-XOR swizzle)
// out[m][n] = sum_k A[m][k]*W[n][k]; fused epilogue.
// =====================================================================
__global__ __launch_bounds__(256) void gemm128(
    const u16* __restrict__ A, int lda,
    const u16* __restrict__ W, int ldw,
    int K, int nbn,
    const float* __restrict__ bias,
    const float* __restrict__ emb, int emb_ld, int ediv, int emod,
    const u16* __restrict__ resid, int ldr,
    int do_relu,
    u16* __restrict__ out, int ldo) {
  __shared__ __align__(16) u16 ldsA[128 * 64];
  __shared__ __align__(16) u16 ldsB[128 * 64];

  const int t = threadIdx.x;
  const int lane = t & 63;
  const int wave = t >> 6;

  const int nwg = gridDim.x;  // multiple of 8
  const int bid = blockIdx.x;
  const int cpx = nwg >> 3;
  const int wg = (bid & 7) * cpx + (bid >> 3);
  const int bm = wg / nbn, bn = wg % nbn;
  const int tile_m = bm * 128, tile_n = bn * 128;

  const int wr = (wave >> 1) * 64;
  const int wc = (wave & 1) * 64;

  f32x4 acc[4][4] = {};

  const int nkt = K >> 6;
  for (int kt = 0; kt < nkt; ++kt) {
    const int k0 = kt << 6;
#pragma unroll
    for (int j = 0; j < 4; ++j) {
      int L = j * 256 + t;
      int row = L >> 3;
      int g8 = (L & 7) ^ (row & 7);
      gload_lds16(A + ((size_t)(tile_m + row) * lda + k0 + g8 * 8), &ldsA[L * 8]);
    }
#pragma unroll
    for (int j = 0; j < 4; ++j) {
      int L = j * 256 + t;
      int row = L >> 3;
      int g8 = (L & 7) ^ (row & 7);
      gload_lds16(W + ((size_t)(tile_n + row) * ldw + k0 + g8 * 8), &ldsB[L * 8]);
    }
    __syncthreads();
#pragma unroll
    for (int kk = 0; kk < 2; ++kk) {
      bf16x8 af[4], bfr[4];
      const int k8 = kk * 4 + (lane >> 4);
#pragma unroll
      for (int mi = 0; mi < 4; ++mi) {
        int r = wr + mi * 16 + (lane & 15);
        af[mi] = *(const bf16x8*)&ldsA[r * 64 + ((k8 ^ (r & 7)) * 8)];
      }
#pragma unroll
      for (int ni = 0; ni < 4; ++ni) {
        int c = wc + ni * 16 + (lane & 15);
        bfr[ni] = *(const bf16x8*)&ldsB[c * 64 + ((k8 ^ (c & 7)) * 8)];
      }
#pragma unroll
      for (int mi = 0; mi < 4; ++mi)
#pragma unroll
        for (int ni = 0; ni < 4; ++ni)
          acc[mi][ni] = __builtin_amdgcn_mfma_f32_16x16x32_bf16(
              af[mi], bfr[ni], acc[mi][ni], 0, 0, 0);
    }
    __syncthreads();
  }

#pragma unroll
  for (int mi = 0; mi < 4; ++mi) {
#pragma unroll
    for (int r = 0; r < 4; ++r) {
      const int grow = tile_m + wr + mi * 16 + (lane >> 4) * 4 + r;
      int eidx = 0;
      if (emb) eidx = uidx(grow, ediv, emod);
#pragma unroll
      for (int ni = 0; ni < 4; ++ni) {
        const int gcol = tile_n + wc + ni * 16 + (lane & 15);
        float v = acc[mi][ni][r];
        if (bias) v += bias[gcol];
        if (emb) v += emb[(size_t)eidx * emb_ld + gcol];
        if (resid) v += bf2f(resid[(size_t)grow * ldr + gcol]);
        if (do_relu) v = fmaxf(v, 0.f);
        out[(size_t)grow * ldo + gcol] = f2bf(v);
      }
    }
  }
}

// =====================================================================
// 256x256-tile 8-phase bf16 MFMA GEMM (T2 swizzle + T3/T4 counted vmcnt
// + T5 setprio). 512 threads = 8 waves (2M x 4N).
// =====================================================================
DEV void stage_tile(const u16* __restrict__ src, int ld, int row0, int k0,
                    u16* ldsbase, int t) {
#pragma unroll
  for (int q = 0; q < 4; ++q) {
    int L = q * 512 + t;
    int row = L >> 3;
    int g8 = (L & 7) ^ (row & 7);
    gload_lds16(src + ((size_t)(row0 + row) * ld + k0 + g8 * 8),
                ldsbase + (size_t)L * 8);
  }
}

DEV bf16x8 frag(const u16* base, int r, int k8) {
  return *(const bf16x8*)(base + r * 64 + ((k8 ^ (r & 7)) << 3));
}

#define PRIO_MFMA(MH, AV, BV)                                              \
  __builtin_amdgcn_s_setprio(1);                                           \
  _Pragma("unroll") for (int mi_ = 0; mi_ < 4; ++mi_) {                    \
    _Pragma("unroll") for (int nj_ = 0; nj_ < 4; ++nj_)                    \
        acc[(MH)*4 + mi_][nj_] = __builtin_amdgcn_mfma_f32_16x16x32_bf16(  \
            AV[mi_], BV[nj_], acc[(MH)*4 + mi_][nj_], 0, 0, 0);            \
  }                                                                        \
  __builtin_amdgcn_s_setprio(0);

#define BAR() __builtin_amdgcn_s_barrier()
#define LGKM0() asm volatile("s_waitcnt lgkmcnt(0)" ::: "memory")

__global__ __launch_bounds__(512, 2) void gemm256(
    const u16* __restrict__ A, int lda,
    const u16* __restrict__ W, int ldw,
    int K, int nbn,
    const float* __restrict__ bias,
    const float* __restrict__ emb, int emb_ld, int ediv, int emod,
    const u16* __restrict__ resid, int ldr,
    int do_relu,
    u16* __restrict__ out, int ldo) {
  __shared__ __align__(16) u16 lds[4][256 * 64];
  u16* AB0 = lds[0]; u16* AB1 = lds[1];
  u16* BB0 = lds[2]; u16* BB1 = lds[3];

  const int t = threadIdx.x;
  const int lane = t & 63;
  const int wave = t >> 6;
  const int lm = lane & 15;
  const int l4 = lane >> 4;

  const int nwg = gridDim.x;  // multiple of 8
  const int bid = blockIdx.x;
  const int cpx = nwg >> 3;
  const int wg = (bid & 7) * cpx + (bid >> 3);
  const int bm = wg / nbn, bn = wg % nbn;
  const int tile_m = bm * 256, tile_n = bn * 256;

  const int wr = (wave >> 2) * 128;
  const int wc = (wave & 3) * 64;

  f32x4 acc[8][4] = {};

  const int nkt = K >> 6;
  const int niter = nkt >> 1;

  stage_tile(A, lda, tile_m, 0, AB0, t);
  stage_tile(W, ldw, tile_n, 0, BB0, t);
  stage_tile(W, ldw, tile_n, 64, BB1, t);
  asm volatile("s_waitcnt vmcnt(4)" ::: "memory");
  BAR();

  for (int it = 0; it < niter; ++it) {
    const bool last = (it == niter - 1);
    const int k0 = it * 128;

    // P1: read t0 k0 (A m0-3 + B); stage A(t1)->AB1
    bf16x8 a0[4], b0[4];
#pragma unroll
    for (int mi = 0; mi < 4; ++mi) a0[mi] = frag(AB0, wr + mi * 16 + lm, l4);
#pragma unroll
    for (int nj = 0; nj < 4; ++nj) b0[nj] = frag(BB0, wc + nj * 16 + lm, l4);
    stage_tile(A, lda, tile_m, k0 + 64, AB1, t);
    BAR(); LGKM0();
    PRIO_MFMA(0, a0, b0)
    BAR();

    // P2: read t0 k0 A m4-7
    bf16x8 a1[4];
#pragma unroll
    for (int mi = 0; mi < 4; ++mi) a1[mi] = frag(AB0, wr + (mi + 4) * 16 + lm, l4);
    BAR(); LGKM0();
    PRIO_MFMA(1, a1, b0)
    BAR();

    // P3: read t0 k1 (A m0-7 + B)
    bf16x8 a2[4], a3[4], b1[4];
#pragma unroll
    for (int mi = 0; mi < 4; ++mi) a2[mi] = frag(AB0, wr + mi * 16 + lm, 4 + l4);
#pragma unroll
    for (int mi = 0; mi < 4; ++mi) a3[mi] = frag(AB0, wr + (mi + 4) * 16 + lm, 4 + l4);
#pragma unroll
    for (int nj = 0; nj < 4; ++nj) b1[nj] = frag(BB0, wc + nj * 16 + lm, 4 + l4);
    BAR(); LGKM0();
    PRIO_MFMA(0, a2, b1)
    BAR();

    // P4: stage A(t2)->AB0; gate for t1
    if (!last) stage_tile(A, lda, tile_m, k0 + 128, AB0, t);
    PRIO_MFMA(1, a3, b1)
    if (last) { asm volatile("s_waitcnt vmcnt(0)" ::: "memory"); }
    else      { asm volatile("s_waitcnt vmcnt(4)" ::: "memory"); }
    BAR();

    // P5: read t1 k0 (A m0-3 + B); stage B(t2)->BB0
    bf16x8 c0[4], d0[4];
#pragma unroll
    for (int mi = 0; mi < 4; ++mi) c0[mi] = frag(AB1, wr + mi * 16 + lm, l4);
#pragma unroll
    for (int nj = 0; nj < 4; ++nj) d0[nj] = frag(BB1, wc + nj * 16 + lm, l4);
    if (!last) stage_tile(W, ldw, tile_n, k0 + 128, BB0, t);
    BAR(); LGKM0();
    PRIO_MFMA(0, c0, d0)
    BAR();

    // P6: read t1 k0 A m4-7
    bf16x8 c1[4];
#pragma unroll
    for (int mi = 0; mi < 4; ++mi) c1[mi] = frag(AB1, wr + (mi + 4) * 16 + lm, l4);
    BAR(); LGKM0();
    PRIO_MFMA(1, c1, d0)
    BAR();

    // P7: read t1 k1 (A m0-7 + B)
    bf16x8 c2[4], c3[4], d1[4];
#pragma unroll
    for (int mi = 0; mi < 4; ++mi) c2[mi] = frag(AB1, wr + mi * 16 + lm, 4 + l4);
#pragma unroll
    for (int mi = 0; mi < 4; ++mi) c3[mi] = frag(AB1, wr + (mi + 4) * 16 + lm, 4 + l4);
#pragma unroll
    for (int nj = 0; nj < 4; ++nj) d1[nj] = frag(BB1, wc + nj * 16 + lm, 4 + l4);
    BAR(); LGKM0();
    PRIO_MFMA(0, c2, d1)
    BAR();

    // P8: stage B(t3)->BB1; gate for t2
    if (!last) stage_tile(W, ldw, tile_n, k0 + 192, BB1, t);
    PRIO_MFMA(1, c3, d1)
    if (!last) {
      asm volatile("s_waitcnt vmcnt(4)" ::: "memory");
      BAR();
    }
  }

#pragma unroll
  for (int mi = 0; mi < 8; ++mi) {
#pragma unroll
    for (int r = 0; r < 4; ++r) {
      const int grow = tile_m + wr + mi * 16 + l4 * 4 + r;
      int eidx = 0;
      if (emb) eidx = uidx(grow, ediv, emod);
#pragma unroll
      for (int nj = 0; nj < 4; ++nj) {
        const int gcol = tile_n + wc + nj * 16 + lm;
        float v = acc[mi][nj][r];
        if (bias) v += bias[gcol];
        if (emb) v += emb[(size_t)eidx * emb_ld + gcol];
        if (resid) v += bf2f(resid[(size_t)grow * ldr + gcol]);
        if (do_relu) v = fmaxf(v, 0.f);
        out[(size_t)grow * ldo + gcol] = f2bf(v);
      }
    }
  }
}

// ---------------- logits = Y(bf16) @ W3.T  (f32 accum, N=7) ----------------
__global__ __launch_bounds__(256) void final_w3(const u16* __restrict__ Y,
                                                const float* __restrict__ W3,
                                                float* __restrict__ out) {
  const int lane = threadIdx.x & 63, wave = threadIdx.x >> 6;
#pragma unroll
  for (int r = 0; r < 4; ++r) {
    const int row = blockIdx.x * 16 + wave * 4 + r;
    float acc[7] = {0, 0, 0, 0, 0, 0, 0};
#pragma unroll
    for (int it = 0; it < 4; ++it) {
      const int k = it * 256 + lane * 4;
      ushort4 yv = *(const ushort4*)(Y + (size_t)row * 1024 + k);
      float y0 = bf2f(yv.x), y1 = bf2f(yv.y), y2 = bf2f(yv.z), y3 = bf2f(yv.w);
#pragma unroll
      for (int n = 0; n < 7; ++n) {
        float4 w = *(const float4*)(W3 + (size_t)n * 1024 + k);
        acc[n] += y0 * w.x + y1 * w.y + y2 * w.z + y3 * w.w;
      }
    }
#pragma unroll
    for (int n = 0; n < 7; ++n)
#pragma unroll
      for (int off = 32; off > 0; off >>= 1)
        acc[n] += __shfl_down(acc[n], off);
    if (lane == 0) {
#pragma unroll
      for (int n = 0; n < 7; ++n) out[(size_t)row * 7 + n] = acc[n];
    }
  }
}

// ---------------- scatter: out[b] = logits[cid(b)] ----------------
__global__ __launch_bounds__(256) void scatter_out(
    const int* __restrict__ items, const int* __restrict__ attr,
    const int* __restrict__ perm, const float* __restrict__ logits,
    float* __restrict__ out) {
  int b = blockIdx.x * 256 + threadIdx.x;
  int cid = ((items[b * 3] * 7 + items[b * 3 + 1]) * 7 + items[b * 3 + 2]) * 9 +
            attr[b] * 3 + perm[b];
  const float* src = logits + (size_t)cid * 7;
  float* dst = out + (size_t)b * 7;
#pragma unroll
  for (int n = 0; n < 7; ++n) dst[n] = src[n];
}

extern "C" void kernel_launch(void* const* d_in, const int* in_sizes, int n_in,
                              void* d_out, int out_size, void* d_ws, size_t ws_size,
                              hipStream_t stream) {
  const int* items = (const int*)d_in[0];
  const int* attr = (const int*)d_in[1];
  const int* perm = (const int*)d_in[2];
  const float* emb_item = (const float*)d_in[3];
  const float* W2 = (const float*)d_in[4];
  const float* W3 = (const float*)d_in[5];
  const float* emb_attr = (const float*)d_in[6];
  const float* W4 = (const float*)d_in[7];
  const float* b4 = (const float*)d_in[8];
  const float* W5 = (const float*)d_in[9];
  const float* W8u = (const float*)d_in[10];
  const float* b8u = (const float*)d_in[11];
  const float* W8d = (const float*)d_in[12];
  const float* b8d = (const float*)d_in[13];
  const float* emb_perm = (const float*)d_in[14];

  const int B = 16384, DIM = 1024, HID = 4096;

  char* ws = (char*)d_ws;
  size_t off = 0;
  auto alloc = [&](size_t bytes) {
    void* p = ws + off;
    off += (bytes + 255) & ~255ull;
    return p;
  };
  u16* W2b = (u16*)alloc((size_t)DIM * DIM * 2);
  u16* W4b = (u16*)alloc((size_t)HID * DIM * 2);
  u16* W5b = (u16*)alloc((size_t)DIM * HID * 2);
  u16* W8ub = (u16*)alloc((size_t)HID * DIM * 2);
  u16* W8db = (u16*)alloc((size_t)DIM * HID * 2);
  u16* Xu0 = (u16*)alloc((size_t)MUPAD * DIM * 2);
  u16* Xu1 = (u16*)alloc((size_t)MUPAD * DIM * 2);
  u16* Hu = (u16*)alloc((size_t)MUPAD * HID * 2);
  float* logits = (float*)alloc((size_t)MUPAD * 7 * 4);

  // weights -> bf16
  cvt_bf16<<<(DIM * DIM / 4 + 255) / 256, 256, 0, stream>>>(W2, W2b, DIM * DIM / 4);
  cvt_bf16<<<(HID * DIM / 4 + 255) / 256, 256, 0, stream>>>(W4, W4b, HID * DIM / 4);
  cvt_bf16<<<(HID * DIM / 4 + 255) / 256, 256, 0, stream>>>(W5, W5b, HID * DIM / 4);
  cvt_bf16<<<(HID * DIM / 4 + 255) / 256, 256, 0, stream>>>(W8u, W8ub, HID * DIM / 4);
  cvt_bf16<<<(HID * DIM / 4 + 255) / 256, 256, 0, stream>>>(W8d, W8db, HID * DIM / 4);

  // unique-row pipeline, M = MUPAD = 3328
  gather0u<<<MUPAD, 256, 0, stream>>>(emb_item, Xu0);

  const int GM128 = MUPAD / 128;  // 26
  const int GM256 = MUPAD / 256;  // 13

  // encoder: state = (emb + state) @ W2^T, with emb index from row id
  gemm128<<<GM128 * (DIM / 128), 256, 0, stream>>>(Xu0, DIM, W2b, DIM, DIM, DIM / 128,
      nullptr, emb_item, DIM, 63, 7, nullptr, 0, 0, Xu1, DIM);
  gemm128<<<GM128 * (DIM / 128), 256, 0, stream>>>(Xu1, DIM, W2b, DIM, DIM, DIM / 128,
      nullptr, emb_item, DIM, 9, 7, nullptr, 0, 0, Xu0, DIM);
  // y = state3 + emb_attr[a(u)]
  gemm128<<<GM128 * (DIM / 128), 256, 0, stream>>>(Xu0, DIM, W2b, DIM, DIM, DIM / 128,
      nullptr, emb_attr, DIM, 3, 3, nullptr, 0, 0, Xu1, DIM);

  // FFN1: H = relu(y@W4^T + b4); y1 = y + H@W5^T
  gemm256<<<GM256 * (HID / 256), 512, 0, stream>>>(Xu1, DIM, W4b, DIM, DIM, HID / 256,
      b4, nullptr, 0, 1, 1, nullptr, 0, 1, Hu, HID);
  gemm128<<<GM128 * (DIM / 128), 256, 0, stream>>>(Hu, HID, W5b, HID, HID, DIM / 128,
      nullptr, nullptr, 0, 1, 1, Xu1, DIM, 0, Xu0, DIM);

  // FFN2: H = relu(y1@W8u^T + b8u + emb_perm[p(u)]); y2 = y1 + H@W8d^T + b8d
  gemm256<<<GM256 * (HID / 256), 512, 0, stream>>>(Xu0, DIM, W8ub, DIM, DIM, HID / 256,
      b8u, emb_perm, HID, 1, 3, nullptr, 0, 1, Hu, HID);
  gemm128<<<GM128 * (DIM / 128), 256, 0, stream>>>(Hu, HID, W8db, HID, HID, DIM / 128,
      b8d, nullptr, 0, 1, 1, Xu0, DIM, 0, Xu1, DIM);

  // logits = y2 @ W3^T
  final_w3<<<MUPAD / 16, 256, 0, stream>>>(Xu1, W3, logits);

  // out[b] = logits[cid(b)]
  scatter_out<<<B / 256, 256, 0, stream>>>(items, attr, perm, logits, (float*)d_out);
}

// Round 5
// 236.953 us; speedup vs baseline: 4.8912x; 1.7831x over previous
//
#include <hip/hip_runtime.h>
#include <hip/hip_bf16.h>

typedef unsigned short u16;
typedef unsigned int u32;
typedef __bf16 bf16x8 __attribute__((ext_vector_type(8)));
typedef float f32x4 __attribute__((ext_vector_type(4)));

#define DEV static __device__ __forceinline__

// Row spaces: v-items (343, pad 384); w2=(v,a) (1029, pad 1152); u=(w2,p) (3087, pad 3328)
#define M3 384
#define M4 1152
#define M5 3328

DEV u16 f2bf(float f) {
  __bf16 b = (__bf16)f;
  return __builtin_bit_cast(u16, b);
}
DEV float bf2f(u16 x) { return __builtin_bit_cast(float, (u32)x << 16); }

DEV void gload_lds16(const void* g, void* l) {
  __builtin_amdgcn_global_load_lds(
      (const __attribute__((address_space(1))) void*)g,
      (__attribute__((address_space(3))) void*)l, 16, 0, 0);
}

// ---------------- all weights f32 -> bf16, one dispatch ----------------
__global__ __launch_bounds__(256) void cvt_all(
    const float* __restrict__ sW2, const float* __restrict__ sW4,
    const float* __restrict__ sW5, const float* __restrict__ sW8u,
    const float* __restrict__ sW8d,
    u16* __restrict__ dW2, u16* __restrict__ dW4, u16* __restrict__ dW5,
    u16* __restrict__ dW8u, u16* __restrict__ dW8d) {
  long t = (long)blockIdx.x * 256 + threadIdx.x;  // 4-elem chunk index
  const float* s;
  u16* d;
  long r = t;
  if (r < 262144) { s = sW2; d = dW2; }
  else {
    r -= 262144;
    int w = (int)(r >> 20);       // / 1048576
    r &= 1048575;
    s = w == 0 ? sW4 : w == 1 ? sW5 : w == 2 ? sW8u : sW8d;
    d = w == 0 ? dW4 : w == 1 ? dW5 : w == 2 ? dW8u : dW8d;
  }
  float4 v = *(const float4*)(s + r * 4);
  ushort4 o;
  o.x = f2bf(v.x); o.y = f2bf(v.y); o.z = f2bf(v.z); o.w = f2bf(v.w);
  *(ushort4*)(d + r * 4) = o;
}

// ---------------- Xe[r] = bf16(emb_item[min(r,6)]), r<128 ----------------
__global__ __launch_bounds__(256) void gatherXe(const float* __restrict__ emb,
                                                u16* __restrict__ out) {
  int r = blockIdx.x;
  int d = threadIdx.x * 4;
  int i0 = r > 6 ? 6 : r;
  float4 v = *(const float4*)(emb + (size_t)i0 * 1024 + d);
  ushort4 o;
  o.x = f2bf(v.x); o.y = f2bf(v.y); o.z = f2bf(v.z); o.w = f2bf(v.w);
  *(ushort4*)(out + (size_t)r * 1024 + d) = o;
}

// =====================================================================
// Split-K 128x128-tile bf16 MFMA GEMM -> f32 partials P[s][m][n].
// P[s*mstride + m*N + n] = sum_{k in chunk s} A[m][k]*W[n][k]
// =====================================================================
__global__ __launch_bounds__(256) void gemm_sk(
    const u16* __restrict__ A, int lda,
    const u16* __restrict__ W, int ldw,
    int kchunk, int nbn, int nsplit,
    float* __restrict__ P, int mstride) {
  __shared__ __align__(16) u16 ldsA[128 * 64];
  __shared__ __align__(16) u16 ldsB[128 * 64];

  const int t = threadIdx.x;
  const int lane = t & 63;
  const int wave = t >> 6;

  const int nwg = gridDim.x;  // always a multiple of 8
  const int bid = blockIdx.x;
  const int cpx = nwg >> 3;
  const int wg = (bid & 7) * cpx + (bid >> 3);
  const int s = wg % nsplit;
  const int tile = wg / nsplit;
  const int bm = tile / nbn, bn = tile % nbn;
  const int N = nbn << 7;
  const int tile_m = bm * 128, tile_n = bn * 128;

  const int wr = (wave >> 1) * 64;
  const int wc = (wave & 1) * 64;

  f32x4 acc[4][4] = {};

  const int kbeg = s * kchunk;
  const int nkt = kchunk >> 6;
  for (int kt = 0; kt < nkt; ++kt) {
    const int k0 = kbeg + (kt << 6);
#pragma unroll
    for (int j = 0; j < 4; ++j) {
      int L = j * 256 + t;
      int row = L >> 3;
      int g8 = (L & 7) ^ (row & 7);
      gload_lds16(A + ((size_t)(tile_m + row) * lda + k0 + g8 * 8), &ldsA[L * 8]);
    }
#pragma unroll
    for (int j = 0; j < 4; ++j) {
      int L = j * 256 + t;
      int row = L >> 3;
      int g8 = (L & 7) ^ (row & 7);
      gload_lds16(W + ((size_t)(tile_n + row) * ldw + k0 + g8 * 8), &ldsB[L * 8]);
    }
    __syncthreads();
#pragma unroll
    for (int kk = 0; kk < 2; ++kk) {
      bf16x8 af[4], bfr[4];
      const int k8 = kk * 4 + (lane >> 4);
#pragma unroll
      for (int mi = 0; mi < 4; ++mi) {
        int r = wr + mi * 16 + (lane & 15);
        af[mi] = *(const bf16x8*)&ldsA[r * 64 + ((k8 ^ (r & 7)) * 8)];
      }
#pragma unroll
      for (int ni = 0; ni < 4; ++ni) {
        int c = wc + ni * 16 + (lane & 15);
        bfr[ni] = *(const bf16x8*)&ldsB[c * 64 + ((k8 ^ (c & 7)) * 8)];
      }
#pragma unroll
      for (int mi = 0; mi < 4; ++mi)
#pragma unroll
        for (int ni = 0; ni < 4; ++ni)
          acc[mi][ni] = __builtin_amdgcn_mfma_f32_16x16x32_bf16(
              af[mi], bfr[ni], acc[mi][ni], 0, 0, 0);
    }
    __syncthreads();
  }

  float* Pb = P + (size_t)s * mstride;
#pragma unroll
  for (int mi = 0; mi < 4; ++mi) {
#pragma unroll
    for (int r = 0; r < 4; ++r) {
      const int grow = tile_m + wr + mi * 16 + (lane >> 4) * 4 + r;
#pragma unroll
      for (int ni = 0; ni < 4; ++ni) {
        const int gcol = tile_n + wc + ni * 16 + (lane & 15);
        Pb[(size_t)grow * N + gcol] = acc[mi][ni][r];
      }
    }
  }
}

// =====================================================================
// reduce + epilogue (+ optional row expansion):
// out[m][c..] = bf16( relu?( sum_s P[s][mc/srcdiv][c] + bias[c]
//                            + emb[mc%emod][c] + resid[mc/rdiv][c] ) )
// mc = min(m, mlast). Grid covers MPAD*N/4 lanes of 4 cols.
// =====================================================================
__global__ __launch_bounds__(256) void reduce_ep(
    const float* __restrict__ P, int N, int mstride, int S,
    int mlast, int srcdiv,
    const float* __restrict__ bias,
    const float* __restrict__ emb, int emod,
    const u16* __restrict__ resid, int rdiv,
    int do_relu, u16* __restrict__ out) {
  int idx = blockIdx.x * 256 + threadIdx.x;
  int npack = N >> 2;
  int m = idx / npack;
  int c = (idx - m * npack) << 2;
  int mc = m > mlast ? mlast : m;
  const float* p0 = P + (size_t)((u32)mc / (u32)srcdiv) * N + c;
  f32x4 v = *(const f32x4*)p0;
  for (int s = 1; s < S; ++s) v += *(const f32x4*)(p0 + (size_t)s * mstride);
  if (bias) v += *(const f32x4*)(bias + c);
  if (emb) v += *(const f32x4*)(emb + (size_t)((u32)mc % (u32)emod) * N + c);
  if (resid) {
    ushort4 rv = *(const ushort4*)(resid + (size_t)((u32)mc / (u32)rdiv) * N + c);
    v.x += bf2f(rv.x); v.y += bf2f(rv.y); v.z += bf2f(rv.z); v.w += bf2f(rv.w);
  }
  if (do_relu) {
    v.x = fmaxf(v.x, 0.f); v.y = fmaxf(v.y, 0.f);
    v.z = fmaxf(v.z, 0.f); v.w = fmaxf(v.w, 0.f);
  }
  ushort4 o;
  o.x = f2bf(v.x); o.y = f2bf(v.y); o.z = f2bf(v.z); o.w = f2bf(v.w);
  *(ushort4*)(out + (size_t)m * N + c) = o;
}

// ---------------- logits = Y2(bf16) @ W3.T  (f32 accum, N=7) ----------------
__global__ __launch_bounds__(256) void final_w3(const u16* __restrict__ Y,
                                                const float* __restrict__ W3,
                                                float* __restrict__ out) {
  const int lane = threadIdx.x & 63, wave = threadIdx.x >> 6;
#pragma unroll
  for (int r = 0; r < 4; ++r) {
    const int row = blockIdx.x * 16 + wave * 4 + r;
    float acc[7] = {0, 0, 0, 0, 0, 0, 0};
#pragma unroll
    for (int it = 0; it < 4; ++it) {
      const int k = it * 256 + lane * 4;
      ushort4 yv = *(const ushort4*)(Y + (size_t)row * 1024 + k);
      float y0 = bf2f(yv.x), y1 = bf2f(yv.y), y2 = bf2f(yv.z), y3 = bf2f(yv.w);
#pragma unroll
      for (int n = 0; n < 7; ++n) {
        float4 w = *(const float4*)(W3 + (size_t)n * 1024 + k);
        acc[n] += y0 * w.x + y1 * w.y + y2 * w.z + y3 * w.w;
      }
    }
#pragma unroll
    for (int n = 0; n < 7; ++n)
#pragma unroll
      for (int off = 32; off > 0; off >>= 1)
        acc[n] += __shfl_down(acc[n], off);
    if (lane == 0) {
#pragma unroll
      for (int n = 0; n < 7; ++n) out[(size_t)row * 7 + n] = acc[n];
    }
  }
}

// ---------------- out[b] = logits[cid(b)] ----------------
__global__ __launch_bounds__(256) void scatter_out(
    const int* __restrict__ items, const int* __restrict__ attr,
    const int* __restrict__ perm, const float* __restrict__ logits,
    float* __restrict__ out) {
  int b = blockIdx.x * 256 + threadIdx.x;
  int cid = ((items[b * 3] * 7 + items[b * 3 + 1]) * 7 + items[b * 3 + 2]) * 9 +
            attr[b] * 3 + perm[b];
  const float* src = logits + (size_t)cid * 7;
  float* dst = out + (size_t)b * 7;
#pragma unroll
  for (int n = 0; n < 7; ++n) dst[n] = src[n];
}

extern "C" void kernel_launch(void* const* d_in, const int* in_sizes, int n_in,
                              void* d_out, int out_size, void* d_ws, size_t ws_size,
                              hipStream_t stream) {
  const int* items = (const int*)d_in[0];
  const int* attr = (const int*)d_in[1];
  const int* perm = (const int*)d_in[2];
  const float* emb_item = (const float*)d_in[3];
  const float* W2 = (const float*)d_in[4];
  const float* W3 = (const float*)d_in[5];
  const float* emb_attr = (const float*)d_in[6];
  const float* W4 = (const float*)d_in[7];
  const float* b4 = (const float*)d_in[8];
  const float* W5 = (const float*)d_in[9];
  const float* W8u = (const float*)d_in[10];
  const float* b8u = (const float*)d_in[11];
  const float* W8d = (const float*)d_in[12];
  const float* b8d = (const float*)d_in[13];
  const float* emb_perm = (const float*)d_in[14];

  const int B = 16384, DIM = 1024, HID = 4096;

  char* ws = (char*)d_ws;
  size_t off = 0;
  auto alloc = [&](size_t bytes) {
    void* p = ws + off;
    off += (bytes + 255) & ~255ull;
    return p;
  };
  u16* W2b = (u16*)alloc((size_t)DIM * DIM * 2);
  u16* W4b = (u16*)alloc((size_t)HID * DIM * 2);
  u16* W5b = (u16*)alloc((size_t)DIM * HID * 2);
  u16* W8ub = (u16*)alloc((size_t)HID * DIM * 2);
  u16* W8db = (u16*)alloc((size_t)DIM * HID * 2);
  u16* Xe = (u16*)alloc((size_t)128 * DIM * 2);
  u16* X2 = (u16*)alloc((size_t)128 * DIM * 2);
  u16* X3 = (u16*)alloc((size_t)M3 * DIM * 2);
  u16* Y = (u16*)alloc((size_t)M4 * DIM * 2);
  u16* H1 = (u16*)alloc((size_t)M4 * HID * 2);
  u16* Y1 = (u16*)alloc((size_t)M4 * DIM * 2);
  u16* H2 = (u16*)alloc((size_t)M5 * HID * 2);
  u16* Y2 = (u16*)alloc((size_t)M5 * DIM * 2);
  float* logits = (float*)alloc((size_t)M5 * 7 * 4);

  // Remaining workspace = split-K partial buffer; adapt split factors to fit.
  size_t avail = ws_size > off ? ws_size - off : 0;
  float* P = (float*)(ws + off);
  auto fits = [&](size_t elems) { return elems * 4 <= avail; };
  const int Se = fits(8ull * M3 * DIM) ? 8 : fits(4ull * M3 * DIM) ? 4 : 2;
  const int Su = fits(2ull * M4 * HID) ? 2 : 1;   // FFN up-proj splits
  const int S5 = fits(8ull * M4 * DIM) ? 8 : fits(4ull * M4 * DIM) ? 4 : 2;
  const int S7 = fits(4ull * M5 * DIM) ? 4 : fits(2ull * M5 * DIM) ? 2 : 1;

  // weights -> bf16 (one dispatch)
  cvt_all<<<17408, 256, 0, stream>>>(W2, W4, W5, W8u, W8d,
                                     W2b, W4b, W5b, W8ub, W8db);

  // Xe[r] = emb_item[min(r,6)]
  gatherXe<<<128, 256, 0, stream>>>(emb_item, Xe);

  // ---- encoder (unique-row spaces 7 -> 49 -> 343 -> 1029) ----
  // G1: state1 = Xe @ W2^T   (M=128)
  gemm_sk<<<8 * Se, 256, 0, stream>>>(Xe, DIM, W2b, DIM, DIM / Se, 8, Se, P, 128 * DIM);
  // X2[w] = state1[w/7] + emb_item[w%7],  w<49
  reduce_ep<<<128, 256, 0, stream>>>(P, DIM, 128 * DIM, Se, 48, 7,
                                     nullptr, emb_item, 7, nullptr, 1, 0, X2);
  // G2: state2 = X2 @ W2^T   (M=128)
  gemm_sk<<<8 * Se, 256, 0, stream>>>(X2, DIM, W2b, DIM, DIM / Se, 8, Se, P, 128 * DIM);
  // X3[v] = state2[v/7] + emb_item[v%7],  v<343
  reduce_ep<<<M3, 256, 0, stream>>>(P, DIM, 128 * DIM, Se, 342, 7,
                                    nullptr, emb_item, 7, nullptr, 1, 0, X3);
  // G3: state3 = X3 @ W2^T   (M=384)
  gemm_sk<<<3 * 8 * Se, 256, 0, stream>>>(X3, DIM, W2b, DIM, DIM / Se, 8, Se, P, M3 * DIM);
  // Y[w2] = state3[w2/3] + emb_attr[w2%3],  w2<1029
  reduce_ep<<<M4, 256, 0, stream>>>(P, DIM, M3 * DIM, Se, 1028, 3,
                                    nullptr, emb_attr, 3, nullptr, 1, 0, Y);

  // ---- FFN1 ----
  gemm_sk<<<9 * 32 * Su, 256, 0, stream>>>(Y, DIM, W4b, DIM, DIM / Su, 32, Su, P, M4 * HID);
  reduce_ep<<<M4 * (HID / 4) / 256, 256, 0, stream>>>(P, HID, M4 * HID, Su, 1028, 1,
                                                      b4, nullptr, 1, nullptr, 1, 1, H1);
  gemm_sk<<<9 * 8 * S5, 256, 0, stream>>>(H1, HID, W5b, HID, HID / S5, 8, S5, P, M4 * DIM);
  reduce_ep<<<M4, 256, 0, stream>>>(P, DIM, M4 * DIM, S5, 1028, 1,
                                    nullptr, nullptr, 1, Y, 1, 0, Y1);

  // ---- FFN2 (GEMM at M=1152; expansion to u-space in the reduce) ----
  gemm_sk<<<9 * 32 * Su, 256, 0, stream>>>(Y1, DIM, W8ub, DIM, DIM / Su, 32, Su, P, M4 * HID);
  // H2[u] = relu(G[u/3] + b8u + emb_perm[u%3]),  u<3087
  reduce_ep<<<M5 * (HID / 4) / 256, 256, 0, stream>>>(P, HID, M4 * HID, Su, 3086, 3,
                                                      b8u, emb_perm, 3, nullptr, 1, 1, H2);
  gemm_sk<<<26 * 8 * S7, 256, 0, stream>>>(H2, HID, W8db, HID, HID / S7, 8, S7, P, M5 * DIM);
  // Y2[u] = H2@W8d^T + b8d + Y1[u/3]
  reduce_ep<<<M5, 256, 0, stream>>>(P, DIM, M5 * DIM, S7, 3086, 1,
                                    b8d, nullptr, 1, Y1, 3, 0, Y2);

  // logits = Y2 @ W3^T
  final_w3<<<M5 / 16, 256, 0, stream>>>(Y2, W3, logits);

  // out[b] = logits[cid(b)]
  scatter_out<<<B / 256, 256, 0, stream>>>(items, attr, perm, logits, (float*)d_out);
}